// Round 5
// baseline (319.968 us; speedup 1.0000x reference)
//
#include <hip/hip_runtime.h>

// YOLO loss on MI355X. Layout:
//   prediction: (N, S, S, 90)  fp32, N=8192, S=7  -> 401408 cells x 90 ch
//   target:     (N, S, S, 85)  fp32               -> 401408 cells x 85 ch
// Output: 6 fp32 scalars.
//
// R9: R7/R8 (NBUF=3, 16x-unrolled asm body) died twice to "container failed
// twice" with no compile/test output (infra-suspect, but not re-risking a
// third identical submit). R9 asks the same question -- does more
// latency-hiding beat R6's 108 us? -- through R6's HARNESS-PROVEN structure
// (double buffer, pointer swap, counted vmcnt, no in-loop barriers),
// re-parameterized for occupancy (TLP) instead of per-wave depth:
//   - CPT=4 cells/tile -> 700-float (2.8 KB) buffers
//   - LDS = 4 waves x 2 x 2.8 KB = 22.4 KB/block -> 7 blocks/CU = 28 waves/CU
//     (87% occupancy; __launch_bounds__(256,7) caps VGPR at 73, have 68)
//   - TPW=16 tiles/wave -> fill overhead 1/16; same 1568-block grid
//   - per tile: 4 gload_lds (wave-uniform count), s_waitcnt vmcnt(4);
//     in-flight ~157 KB/CU from TLP (28 waves x 4-8 loads x 1.4 KB)
//   - rolled loop, cur/nxt pointer swap -- small codegen, no unrolled asm
//   - compute: 16 lanes/cell x 5 class channels = 80 exactly; part==0 lanes
//     do box/conf; stride-5 LDS reads = ~2-way bank aliasing (free, m136)
// Grid: 1568 blocks x 4 waves x 16 tiles x 4 cells = 401408 cells exactly.

#define NCELLS (8192 * 49)                  // 401408
#define CPT 4                               // cells per wave-tile
#define TPW 16                              // tiles per wave
#define WPB 4                               // waves per block
#define CELLS_PER_BLOCK (CPT * TPW * WPB)   // 256
#define NBLOCKS (NCELLS / CELLS_PER_BLOCK)  // 1568
#define TFL (CPT * 85)                      // 340 floats of tgt per tile
#define PFL (CPT * 90)                      // 360 floats of pred per tile
#define BUF_FL (TFL + PFL)                  // 700 floats = 2800 B per buffer

constexpr float BSF = 8192.0f;

__device__ __forceinline__ void g2lds16(const float* g, float* s) {
    __builtin_amdgcn_global_load_lds(
        (const __attribute__((address_space(1))) void*)g,
        (__attribute__((address_space(3))) void*)s,
        16, 0, 0);
}

__device__ __forceinline__ void rel2abs(float x, float y, float w, float h,
                                        float fi, float fj,
                                        float& x1, float& y1, float& x2, float& y2) {
    float xc = (x + fj) / 7.0f;
    float yc = (y + fi) / 7.0f;
    float hw = w * 0.5f, hh = h * 0.5f;
    x1 = xc - hw; y1 = yc - hh; x2 = xc + hw; y2 = yc + hh;
}

__device__ __forceinline__ float iou_abs(float ax1, float ay1, float ax2, float ay2,
                                         float bx1, float by1, float bx2, float by2) {
    float iw = fminf(ax2, bx2) - fmaxf(ax1, bx1); iw = fmaxf(iw, 0.0f);
    float ih = fminf(ay2, by2) - fmaxf(ay1, by1); ih = fmaxf(ih, 0.0f);
    float inter  = iw * ih;
    float area_a = (ax2 - ax1) * (ay2 - ay1);
    float area_b = (bx2 - bx1) * (by2 - by1);
    return inter / (area_a + area_b - inter + 1e-6f);
}

// Stage one 4-cell tile into a wave-private LDS buffer. Layout:
//   wbuf[0 .. 340)   = 4 target rows (85 floats each) = 85 chunks (64 + 21)
//   wbuf[340 .. 700) = 4 pred rows   (90 floats each) = 90 chunks (64 + 26)
// Exactly 4 gload_lds issued per wave per tile (tail loads: exec is never 0
// for lanes<21 / lanes<26, so the instruction always issues and counts) ->
// vmcnt accounting is wave-uniform at 4/tile. LDS dest = wave-uniform base
// + lane*16 (DMA constraint); exec-disabled lanes write nothing. All bases
// 16B-aligned (tile strides 1360 B / 1440 B; TFL offset 1360 B).
__device__ __forceinline__ void stage_tile(const float* __restrict__ tg,
                                           const float* __restrict__ pg,
                                           float* wbuf, int lane) {
    g2lds16(tg + 4 * lane, wbuf + 4 * lane);
    if (lane < 21) g2lds16(tg + 256 + 4 * lane, wbuf + 256 + 4 * lane);
    g2lds16(pg + 4 * lane, wbuf + TFL + 4 * lane);
    if (lane < 26) g2lds16(pg + 256 + 4 * lane, wbuf + TFL + 256 + 4 * lane);
}

__global__ __launch_bounds__(256, 7) void yolo_main(const float* __restrict__ pred,
                                                    const float* __restrict__ tgt,
                                                    float* __restrict__ acc,
                                                    int nrep, int sstride) {
    __shared__ __align__(16) float lds[WPB][2][BUF_FL];   // 22400 B
    __shared__ float smr[WPB * 5];

    const int tid  = threadIdx.x;
    const int lane = tid & 63;
    const int wid  = tid >> 6;

    const int wave_id = blockIdx.x * WPB + wid;
    const int tile0   = wave_id * TPW;

    const float* tg0 = tgt  + (size_t)tile0 * TFL;
    const float* pg0 = pred + (size_t)tile0 * PFL;

    float a_xy = 0.f, a_wh = 0.f, a_co = 0.f, a_cn = 0.f, a_cl = 0.f;

    const int cell = lane >> 4;        // 0..3: cell within tile
    const int part = lane & 15;        // 0..15: 5-channel class slice
    const int c0   = 5 * part;

    float* cur = &lds[wid][0][0];
    float* nxt = &lds[wid][1][0];

    // prologue: prefetch tile 0
    stage_tile(tg0, pg0, cur, lane);

    for (int k = 0; k < TPW; ++k) {
        if (k + 1 < TPW) {
            // nxt was last ds_read by THIS wave at tile k-1: fence my reads,
            // then overwrite it with tile k+1, then wait for tile k's 4 loads.
            asm volatile("s_waitcnt lgkmcnt(0)" ::: "memory");
            stage_tile(tg0 + (size_t)(k + 1) * TFL,
                       pg0 + (size_t)(k + 1) * PFL, nxt, lane);
            asm volatile("s_waitcnt vmcnt(4)" ::: "memory");   // tile k landed
        } else {
            asm volatile("s_waitcnt vmcnt(0)" ::: "memory");
        }

        // ---------- compute tile k (wave-private, no barrier) ----------
        const float* tb = cur + 85 * cell;
        const float* pb = cur + TFL + 90 * cell;

        const float objf = (tb[4] != 0.0f) ? 1.0f : 0.0f;

        float s = 0.f;
        #pragma unroll
        for (int c = 0; c < 5; ++c) {
            float d = tb[5 + c0 + c] - pb[10 + c0 + c];
            s = fmaf(d, d, s);
        }
        a_cl += objf * s;

        if (part == 0) {
            float tx = tb[0], ty = tb[1], tw = tb[2], th = tb[3], tc = tb[4];
            float p0x = pb[0], p0y = pb[1], p0w = pb[2], p0h = pb[3];
            float p1x = pb[5], p1y = pb[6], p1w = pb[7], p1h = pb[8];
            float pc  = pb[9];                 // pred_c = prediction[..., 9]

            int gcell = (tile0 + k) * CPT + cell;
            int sij   = gcell % 49;
            float fi  = (float)(sij / 7);
            float fj  = (float)(sij % 7);

            float t1, t2, t3, t4, a1, a2, a3, a4, b1, b2, b3, b4;
            rel2abs(tx,  ty,  tw,  th,  fi, fj, t1, t2, t3, t4);
            rel2abs(p0x, p0y, p0w, p0h, fi, fj, a1, a2, a3, a4);
            rel2abs(p1x, p1y, p1w, p1h, fi, fj, b1, b2, b3, b4);

            float iou0 = iou_abs(t1, t2, t3, t4, a1, a2, a3, a4);
            float iou1 = iou_abs(t1, t2, t3, t4, b1, b2, b3, b4);

            bool sel = iou0 > iou1;   // ref: where(iou0>iou1, pred[5:10], pred[0:5])
            float xh = sel ? p1x : p0x;
            float yh = sel ? p1y : p0y;
            float wh = sel ? p1w : p0w;
            float hh = sel ? p1h : p0h;

            float dx = tx - xh, dy = ty - yh;
            a_xy += objf * (dx * dx + dy * dy);

            float sw = sqrtf(tw) - sqrtf(fmaxf(wh, 0.0f));
            float sh = sqrtf(th) - sqrtf(fmaxf(hh, 0.0f));
            a_wh += objf * (sw * sw + sh * sh);

            float ce = tc - pc; ce *= ce;
            a_co += objf * ce;
            a_cn += (1.0f - objf) * ce;
        }

        float* tmp = cur; cur = nxt; nxt = tmp;   // swap buffers
    }

    // ---------- reduce: wave shfl -> LDS -> spread atomics ----------
    #pragma unroll
    for (int off = 32; off; off >>= 1) {
        a_xy += __shfl_down(a_xy, off, 64);
        a_wh += __shfl_down(a_wh, off, 64);
        a_co += __shfl_down(a_co, off, 64);
        a_cn += __shfl_down(a_cn, off, 64);
        a_cl += __shfl_down(a_cl, off, 64);
    }
    if (lane == 0) {
        smr[wid * 5 + 0] = a_xy; smr[wid * 5 + 1] = a_wh; smr[wid * 5 + 2] = a_co;
        smr[wid * 5 + 3] = a_cn; smr[wid * 5 + 4] = a_cl;
    }
    __syncthreads();   // the ONLY block-wide sync
    if (tid == 0) {
        float s0 = 0.f, s1 = 0.f, s2 = 0.f, s3 = 0.f, s4 = 0.f;
        #pragma unroll
        for (int w = 0; w < 4; ++w) {
            s0 += smr[w * 5 + 0]; s1 += smr[w * 5 + 1]; s2 += smr[w * 5 + 2];
            s3 += smr[w * 5 + 3]; s4 += smr[w * 5 + 4];
        }
        const int rep = (int)(blockIdx.x & (unsigned)(nrep - 1));
        float* a0 = acc + (size_t)rep * 5 * sstride;
        atomicAdd(&a0[0 * sstride], s0);
        atomicAdd(&a0[1 * sstride], s1);
        atomicAdd(&a0[2 * sstride], s2);
        atomicAdd(&a0[3 * sstride], s3);
        atomicAdd(&a0[4 * sstride], s4);
    }
}

__global__ void yolo_finalize(const float* __restrict__ acc, float* __restrict__ out,
                              int nrep, int sstride) {
    if (threadIdx.x == 0 && blockIdx.x == 0) {
        float s[5] = {0.f, 0.f, 0.f, 0.f, 0.f};
        for (int r = 0; r < nrep; ++r)
            for (int k = 0; k < 5; ++k)
                s[k] += acc[((size_t)r * 5 + k) * sstride];
        float lxy = s[0] / BSF;
        float lwh = s[1] / BSF;
        float lco = s[2] / BSF;
        float lcn = s[3] / BSF;
        float lcl = s[4] / BSF;
        out[0] = (5.0f * lxy + 5.0f * lwh + lco + 0.5f * lcn + lcl) / BSF;
        out[1] = lxy;
        out[2] = lwh;
        out[3] = lco;
        out[4] = lcn;
        out[5] = lcl;
    }
}

extern "C" void kernel_launch(void* const* d_in, const int* in_sizes, int n_in,
                              void* d_out, int out_size, void* d_ws, size_t ws_size,
                              hipStream_t stream) {
    const float* pred = (const float*)d_in[0];
    const float* tgt  = (const float*)d_in[1];
    float* out = (float*)d_out;
    float* acc = (float*)d_ws;

    // 8 replicas x 5 counters, one 128B line per counter slot (stride 32
    // floats) -> 5120 B. Fall back to the compact 20 B layout if ws is tiny.
    int nrep, sstride; size_t zbytes;
    if (ws_size >= 8 * 5 * 32 * sizeof(float)) { nrep = 8; sstride = 32; zbytes = 8 * 5 * 32 * sizeof(float); }
    else                                       { nrep = 1; sstride = 1;  zbytes = 5 * sizeof(float); }

    // d_ws is poisoned (0xAA) before every timed launch -> must zero here.
    hipMemsetAsync(acc, 0, zbytes, stream);

    yolo_main<<<NBLOCKS, 256, 0, stream>>>(pred, tgt, acc, nrep, sstride);
    yolo_finalize<<<1, 64, 0, stream>>>(acc, out, nrep, sstride);
}

// Round 6
// 314.157 us; speedup vs baseline: 1.0185x; 1.0185x over previous
//
#include <hip/hip_runtime.h>

// YOLO loss on MI355X. Layout:
//   prediction: (N, S, S, 90)  fp32, N=8192, S=7  -> 401408 cells x 90 ch
//   target:     (N, S, S, 85)  fp32               -> 401408 cells x 85 ch
// Output: 6 fp32 scalars.
//
// R10: the 4-point ablation (R4 143us depth-0 / R5 118us counted-vmcnt /
// R6 108us wave-private@12w / R9 130us wave-private@28w) shows every
// global_load_lds-staged variant pins at ~2.0-2.6 TB/s (~4 B/cy/CU),
// INSENSITIVE to sync structure, depth, and occupancy. Little's law at the
// nominal in-flight bytes implies multi-us request latency -> the LDS-DMA
// path itself is the cap for L3/HBM-sourced streams (a gload_lds retires
// only when all 64 lane-fills land; the CU sustains only a few 1KB fills
// in flight: ~4KB/900cy = 4.5 B/cy -- matches all four points. m97's
// 22 B/cy/CU via gload_lds was L2-resident data).
// Fix: NO LDS AT ALL -- direct-to-VGPR loads through the normal per-lane
// MSHR path (the machinery that hits 6.3 TB/s in the float4-copy bench):
//   - 8 lanes/cell, lane p owns class channels [10p, 10p+10)
//   - per lane: 10 scalar tgt loads + 5 float2 pred loads (8B-aligned:
//     (90c+10+10p+2m) is even; pred base 256B-aligned); objf via broadcast
//     load of tb[4] (same-address lanes merge in the coalescer)
//   - wave spans 4 cell rows per load instr -> ~5-7x TA-segment inflation,
//     L1-absorbed (segments reused across the unrolled channel loads);
//     L2/L3/HBM traffic stays at the ideal 281 MB
//   - box/conf on p==0 lanes (predicated, ~9 wave-instrs/cell)
//   - zero arrays / static indices only (R3 scratch-demotion lesson);
//     no in-loop waits or barriers; VGPR-light -> high occupancy
// Grid: 1568 blocks x 8 iters x 4 waves x 8 cells = 401408 cells exactly.

#define NCELLS (8192 * 49)                  // 401408
#define NITER 8
#define CELLS_PER_BLOCK 256                 // 8 iters x 4 waves x 8 cells
#define NBLOCKS (NCELLS / CELLS_PER_BLOCK)  // 1568

constexpr float BSF = 8192.0f;

__device__ __forceinline__ void rel2abs(float x, float y, float w, float h,
                                        float fi, float fj,
                                        float& x1, float& y1, float& x2, float& y2) {
    float xc = (x + fj) / 7.0f;
    float yc = (y + fi) / 7.0f;
    float hw = w * 0.5f, hh = h * 0.5f;
    x1 = xc - hw; y1 = yc - hh; x2 = xc + hw; y2 = yc + hh;
}

__device__ __forceinline__ float iou_abs(float ax1, float ay1, float ax2, float ay2,
                                         float bx1, float by1, float bx2, float by2) {
    float iw = fminf(ax2, bx2) - fmaxf(ax1, bx1); iw = fmaxf(iw, 0.0f);
    float ih = fminf(ay2, by2) - fmaxf(ay1, by1); ih = fmaxf(ih, 0.0f);
    float inter  = iw * ih;
    float area_a = (ax2 - ax1) * (ay2 - ay1);
    float area_b = (bx2 - bx1) * (by2 - by1);
    return inter / (area_a + area_b - inter + 1e-6f);
}

__global__ __launch_bounds__(256, 6) void yolo_main(const float* __restrict__ pred,
                                                    const float* __restrict__ tgt,
                                                    float* __restrict__ acc,
                                                    int nrep, int sstride) {
    __shared__ float smr[4 * 5];

    const int tid  = threadIdx.x;
    const int lane = tid & 63;
    const int wid  = tid >> 6;
    const int c8   = lane >> 3;     // 0..7: cell within wave's 8-cell group
    const int p    = lane & 7;      // 0..7: 10-channel class slice

    float a_xy = 0.f, a_wh = 0.f, a_co = 0.f, a_cn = 0.f, a_cl = 0.f;

    const int cell0 = blockIdx.x * CELLS_PER_BLOCK + wid * 8 + c8;

    #pragma unroll 2
    for (int k = 0; k < NITER; ++k) {
        const int cell = cell0 + k * 32;
        const float* tb = tgt  + (size_t)cell * 85;
        const float* pb = pred + (size_t)cell * 90;

        const float tc   = tb[4];                    // broadcast within cell group
        const float objf = (tc != 0.0f) ? 1.0f : 0.0f;

        // ---- class SSE: this lane's 10 channels [10p, 10p+10) ----
        const float* tcl = tb + 5  + 10 * p;         // scalar (parity unknown)
        const float* pcl = pb + 10 + 10 * p;         // even dword offset -> 8B ok
        float s = 0.f;
        #pragma unroll
        for (int m = 0; m < 5; ++m) {
            const float2 pv = *reinterpret_cast<const float2*>(pcl + 2 * m);
            const float t0 = tcl[2 * m];
            const float t1 = tcl[2 * m + 1];
            const float d0 = t0 - pv.x;
            const float d1 = t1 - pv.y;
            s = fmaf(d0, d0, s);
            s = fmaf(d1, d1, s);
        }
        a_cl += objf * s;

        // ---- box + conf: one lane per cell (p == 0), predicated ----
        if (p == 0) {
            const float tx = tb[0], ty = tb[1], tw = tb[2], th = tb[3];
            const float2 q01 = *reinterpret_cast<const float2*>(pb + 0);  // p0x p0y
            const float2 q23 = *reinterpret_cast<const float2*>(pb + 2);  // p0w p0h
            const float2 q45 = *reinterpret_cast<const float2*>(pb + 4);  // c0  p1x
            const float2 q67 = *reinterpret_cast<const float2*>(pb + 6);  // p1y p1w
            const float2 q89 = *reinterpret_cast<const float2*>(pb + 8);  // p1h pc
            const float p0x = q01.x, p0y = q01.y, p0w = q23.x, p0h = q23.y;
            const float p1x = q45.y, p1y = q67.x, p1w = q67.y, p1h = q89.x;
            const float pc  = q89.y;               // pred_c = prediction[..., 9]

            const int sij = cell % 49;
            const float fi = (float)(sij / 7);
            const float fj = (float)(sij % 7);

            float t1_, t2_, t3_, t4_, a1, a2, a3, a4, b1, b2, b3, b4;
            rel2abs(tx,  ty,  tw,  th,  fi, fj, t1_, t2_, t3_, t4_);
            rel2abs(p0x, p0y, p0w, p0h, fi, fj, a1, a2, a3, a4);
            rel2abs(p1x, p1y, p1w, p1h, fi, fj, b1, b2, b3, b4);

            const float iou0 = iou_abs(t1_, t2_, t3_, t4_, a1, a2, a3, a4);
            const float iou1 = iou_abs(t1_, t2_, t3_, t4_, b1, b2, b3, b4);

            const bool sel = iou0 > iou1;  // ref: where(iou0>iou1, pred[5:10], pred[0:5])
            const float xh = sel ? p1x : p0x;
            const float yh = sel ? p1y : p0y;
            const float wh = sel ? p1w : p0w;
            const float hh = sel ? p1h : p0h;

            const float dx = tx - xh, dy = ty - yh;
            a_xy += objf * (dx * dx + dy * dy);

            const float sw = sqrtf(tw) - sqrtf(fmaxf(wh, 0.0f));
            const float sh = sqrtf(th) - sqrtf(fmaxf(hh, 0.0f));
            a_wh += objf * (sw * sw + sh * sh);

            float ce = tc - pc; ce *= ce;
            a_co += objf * ce;
            a_cn += (1.0f - objf) * ce;
        }
    }

    // ---------- reduce: wave shfl -> LDS -> spread atomics ----------
    #pragma unroll
    for (int off = 32; off; off >>= 1) {
        a_xy += __shfl_down(a_xy, off, 64);
        a_wh += __shfl_down(a_wh, off, 64);
        a_co += __shfl_down(a_co, off, 64);
        a_cn += __shfl_down(a_cn, off, 64);
        a_cl += __shfl_down(a_cl, off, 64);
    }
    if (lane == 0) {
        smr[wid * 5 + 0] = a_xy; smr[wid * 5 + 1] = a_wh; smr[wid * 5 + 2] = a_co;
        smr[wid * 5 + 3] = a_cn; smr[wid * 5 + 4] = a_cl;
    }
    __syncthreads();
    if (tid == 0) {
        float s0 = 0.f, s1 = 0.f, s2 = 0.f, s3 = 0.f, s4 = 0.f;
        #pragma unroll
        for (int w = 0; w < 4; ++w) {
            s0 += smr[w * 5 + 0]; s1 += smr[w * 5 + 1]; s2 += smr[w * 5 + 2];
            s3 += smr[w * 5 + 3]; s4 += smr[w * 5 + 4];
        }
        const int rep = (int)(blockIdx.x & (unsigned)(nrep - 1));
        float* a0 = acc + (size_t)rep * 5 * sstride;
        atomicAdd(&a0[0 * sstride], s0);
        atomicAdd(&a0[1 * sstride], s1);
        atomicAdd(&a0[2 * sstride], s2);
        atomicAdd(&a0[3 * sstride], s3);
        atomicAdd(&a0[4 * sstride], s4);
    }
}

__global__ void yolo_finalize(const float* __restrict__ acc, float* __restrict__ out,
                              int nrep, int sstride) {
    if (threadIdx.x == 0 && blockIdx.x == 0) {
        float s[5] = {0.f, 0.f, 0.f, 0.f, 0.f};
        for (int r = 0; r < nrep; ++r)
            for (int k = 0; k < 5; ++k)
                s[k] += acc[((size_t)r * 5 + k) * sstride];
        float lxy = s[0] / BSF;
        float lwh = s[1] / BSF;
        float lco = s[2] / BSF;
        float lcn = s[3] / BSF;
        float lcl = s[4] / BSF;
        out[0] = (5.0f * lxy + 5.0f * lwh + lco + 0.5f * lcn + lcl) / BSF;
        out[1] = lxy;
        out[2] = lwh;
        out[3] = lco;
        out[4] = lcn;
        out[5] = lcl;
    }
}

extern "C" void kernel_launch(void* const* d_in, const int* in_sizes, int n_in,
                              void* d_out, int out_size, void* d_ws, size_t ws_size,
                              hipStream_t stream) {
    const float* pred = (const float*)d_in[0];
    const float* tgt  = (const float*)d_in[1];
    float* out = (float*)d_out;
    float* acc = (float*)d_ws;

    // 8 replicas x 5 counters, one 128B line per counter slot (stride 32
    // floats) -> 5120 B. Fall back to the compact 20 B layout if ws is tiny.
    int nrep, sstride; size_t zbytes;
    if (ws_size >= 8 * 5 * 32 * sizeof(float)) { nrep = 8; sstride = 32; zbytes = 8 * 5 * 32 * sizeof(float); }
    else                                       { nrep = 1; sstride = 1;  zbytes = 5 * sizeof(float); }

    // d_ws is poisoned (0xAA) before every timed launch -> must zero here.
    hipMemsetAsync(acc, 0, zbytes, stream);

    yolo_main<<<NBLOCKS, 256, 0, stream>>>(pred, tgt, acc, nrep, sstride);
    yolo_finalize<<<1, 64, 0, stream>>>(acc, out, nrep, sstride);
}